// Round 2
// baseline (29657.993 us; speedup 1.0000x reference)
//
#include <hip/hip_runtime.h>
#include <hip/hip_bf16.h>

// EnsembleRSSM observe scan — single persistent kernel with manual grid barrier.
// B=256, T=64, STOCH=32, DETER=1024, HIDDEN=1024, EMBED=1536, ACT=6, ENS=5.
// Grid: 256 blocks x 512 threads (8 waves) — co-resident (grid <= 256 CUs).
// Per step: [GEMM1 gru] bar [gates/LN] bar [GEMM2 heads] bar [dist+prep] bar.

#define B_ 256
#define T_ 64
#define ACT_ 6
#define OUTW_ 1216
#define GRID_ 256
#define NT_ 512

typedef __attribute__((ext_vector_type(8))) short bf16x8;
typedef __attribute__((ext_vector_type(4))) float f32x4;

__device__ inline unsigned short f2bf(float x) {
    union { float f; unsigned int u; } v; v.f = x;
    unsigned int r = v.u + 0x7fffu + ((v.u >> 16) & 1u);
    return (unsigned short)(r >> 16);
}
__device__ inline float softplus_f(float x) { return x > 20.f ? x : log1pf(expf(x)); }
__device__ inline float sigmoid_f(float x) { return 1.f / (1.f + expf(-x)); }
__device__ inline float elu_f(float x) { return x > 0.f ? x : expm1f(x); }

// ---- device-scope grid barrier (generation-based) -------------------------
__device__ inline void gbar(unsigned* cnt, unsigned* gen) {
    __threadfence();                 // release: all threads' stores -> agent visible
    __syncthreads();
    if (threadIdx.x == 0) {
        unsigned g = __hip_atomic_load(gen, __ATOMIC_RELAXED, __HIP_MEMORY_SCOPE_AGENT);
        unsigned a = __hip_atomic_fetch_add(cnt, 1u, __ATOMIC_ACQ_REL, __HIP_MEMORY_SCOPE_AGENT);
        if (a == GRID_ - 1) {
            __hip_atomic_store(cnt, 0u, __ATOMIC_RELAXED, __HIP_MEMORY_SCOPE_AGENT);
            __hip_atomic_fetch_add(gen, 1u, __ATOMIC_RELEASE, __HIP_MEMORY_SCOPE_AGENT);
        } else {
            while (__hip_atomic_load(gen, __ATOMIC_RELAXED, __HIP_MEMORY_SCOPE_AGENT) == g)
                __builtin_amdgcn_s_sleep(4);
        }
    }
    __syncthreads();
    __threadfence();                 // acquire side for every thread
}

// ---- MFMA 32x32 tile helper (MF=2,NF=2), A[M,K] bf16 row-major, Bt[N,K] ----
__device__ inline void mfma22(const unsigned short* __restrict__ A, int lda,
                              const unsigned short* __restrict__ Bt, int ldb,
                              int niter, int row0, int col0, f32x4 acc[2][2]) {
    int lane = threadIdx.x & 63;
    int lr = lane & 15, q = lane >> 4;
    const unsigned short* ap = A + (size_t)(row0 + lr) * lda + q * 8;
    const unsigned short* bp = Bt + (size_t)(col0 + lr) * ldb + q * 8;
    for (int it = 0; it < niter; ++it) {
        int k = it * 32;
        bf16x8 a0 = *(const bf16x8*)(ap + k);
        bf16x8 a1 = *(const bf16x8*)(ap + (size_t)16 * lda + k);
        bf16x8 b0 = *(const bf16x8*)(bp + k);
        bf16x8 b1 = *(const bf16x8*)(bp + (size_t)16 * ldb + k);
        acc[0][0] = __builtin_amdgcn_mfma_f32_16x16x32_bf16(a0, b0, acc[0][0], 0, 0, 0);
        acc[0][1] = __builtin_amdgcn_mfma_f32_16x16x32_bf16(a0, b1, acc[0][1], 0, 0, 0);
        acc[1][0] = __builtin_amdgcn_mfma_f32_16x16x32_bf16(a1, b0, acc[1][0], 0, 0, 0);
        acc[1][1] = __builtin_amdgcn_mfma_f32_16x16x32_bf16(a1, b1, acc[1][1], 0, 0, 0);
    }
}
__device__ inline void store22(float* __restrict__ dst, int ld, int row0, int col0,
                               f32x4 acc[2][2]) {
    int lane = threadIdx.x & 63;
    int lr = lane & 15, q = lane >> 4;
#pragma unroll
    for (int i = 0; i < 2; i++)
#pragma unroll
        for (int j = 0; j < 2; j++)
#pragma unroll
            for (int r = 0; r < 4; r++)
                dst[(size_t)(row0 + i * 16 + q * 4 + r) * ld + col0 + j * 16 + lr] = acc[i][j][r];
}

__global__ __launch_bounds__(NT_)
void rssm_persistent(
    const float* __restrict__ embed, const float* __restrict__ action,
    const float* __restrict__ eps_post, const float* __restrict__ eps_prior,
    const unsigned char* __restrict__ is_first, const int* __restrict__ ens_idx,
    const float* __restrict__ W_gru, const float* __restrict__ b_gru,
    const float* __restrict__ ln_g, const float* __restrict__ ln_b,
    const float* __restrict__ W_inp, const float* __restrict__ b_inp,
    const float* __restrict__ W_obs, const float* __restrict__ b_obs,
    const float* __restrict__ W_ens, const float* __restrict__ b_ens,
    const float* __restrict__ Wod, const float* __restrict__ bod,
    const float* __restrict__ Wed, const float* __restrict__ bed,
    float* __restrict__ out,
    unsigned* bar_cnt, unsigned* bar_gen,
    unsigned short* __restrict__ Wt_gru, unsigned short* __restrict__ Wt_obs,
    unsigned short* __restrict__ Wt_ens,
    unsigned short* __restrict__ xcat, unsigned short* __restrict__ dcat,
    unsigned short* __restrict__ dnew_bf,
    float* __restrict__ G0, float* __restrict__ G1,
    float* __restrict__ h0, float* __restrict__ h1,
    float* __restrict__ xo0, float* __restrict__ xo1,
    float* __restrict__ xo2, float* __restrict__ xo3)
{
    __shared__ float s_tile[32][33];
    __shared__ float s_h[1024], s_xo[1024];
    __shared__ float s_dm[1024], s_deter[1024];
    __shared__ float s_acc[512], s_tot[128];
    __shared__ float s_stoch[32], s_am[8];
    __shared__ float s_red1[8], s_red2[8], s_mv[2];

    const int tid = threadIdx.x;
    const int bb = blockIdx.x;
    const int wid = tid >> 6;

    // ---------------- phase T: weight transpose + bf16 convert -------------
    {
        int tx = tid & 31, ty = tid >> 5;  // 32 x 16
        for (int task = bb; task < 13824; task += GRID_) {
            const float* src; unsigned short* dst; int K, N, n0, k0;
            if (task < 6144) {
                src = W_gru; dst = Wt_gru; K = 2048; N = 3072;
                n0 = (task % 96) * 32; k0 = (task / 96) * 32;
            } else if (task < 8704) {
                int i = task - 6144;
                src = W_obs; dst = Wt_obs; K = 2560; N = 1024;
                n0 = (i & 31) * 32; k0 = (i >> 5) * 32;
            } else {
                int i = task - 8704; int e = i >> 10; int r = i & 1023;
                src = W_ens + (size_t)e * 1048576; dst = Wt_ens + (size_t)e * 1048576;
                K = 1024; N = 1024;
                n0 = (r & 31) * 32; k0 = (r >> 5) * 32;
            }
            for (int i = ty; i < 32; i += 16)
                s_tile[i][tx] = src[(size_t)(k0 + i) * N + n0 + tx];
            __syncthreads();
            for (int i = ty; i < 32; i += 16)
                dst[(size_t)(n0 + i) * K + k0 + tx] = f2bf(s_tile[tx][i]);
            __syncthreads();
        }
    }

    // ---------------- phase P0: init state + prep step 0 --------------------
    {
        const int b = bb;
        for (int i = tid; i < 1024; i += NT_) { s_deter[i] = 0.f; s_dm[i] = 0.f; }
        if (tid < 32) s_stoch[tid] = 0.f;
        __syncthreads();
        float m = is_first[b * T_ + 0] ? 0.f : 1.f;
        if (tid < ACT_) s_am[tid] = action[((size_t)b * T_) * ACT_ + tid] * m;
        __syncthreads();
        for (int n = tid; n < 1024; n += NT_) {
            float a = b_inp[n];
#pragma unroll
            for (int k = 0; k < ACT_; k++) a += s_am[k] * W_inp[(32 + k) * 1024 + n];
            xcat[(size_t)b * 2048 + n] = f2bf(elu_f(a));
            xcat[(size_t)b * 2048 + 1024 + n] = 0;  // deter = 0
        }
        for (int j = tid; j < 1536; j += NT_)
            dcat[(size_t)b * 2560 + 1024 + j] = f2bf(embed[((size_t)b * T_) * 1536 + j]);
    }
    gbar(bar_cnt, bar_gen);

    // ---------------- main scan ---------------------------------------------
    for (int t = 0; t < T_; ++t) {
        // ---- GEMM1: G = xcat[256,2048] @ Wt_gru^T -> 3072 cols, K-split 2 --
        // blocks 0..191: ks = bb/96, col-tile = bb%96 (XCD-local pairs b, b+96)
        if (bb < 192) {
            int ks = bb / 96;
            int col0 = (bb % 96) * 32;
            int row0 = wid * 32;
            f32x4 acc[2][2];
#pragma unroll
            for (int i = 0; i < 2; i++)
#pragma unroll
                for (int j = 0; j < 2; j++) { f32x4 z = {0.f,0.f,0.f,0.f}; acc[i][j] = z; }
            mfma22(xcat + ks * 1024, 2048, Wt_gru + ks * 1024, 2048, 32, row0, col0, acc);
            store22(ks ? G1 : G0, 3072, row0, col0, acc);
        }
        gbar(bar_cnt, bar_gen);

        // ---- gates/LN: block b <-> row b -----------------------------------
        {
            const int b = bb;
            float gv[2][3];
            float s1 = 0.f, s2 = 0.f;
#pragma unroll
            for (int u = 0; u < 2; ++u) {
                int j = tid + u * NT_;
                size_t base = (size_t)b * 3072 + j;
                float g0 = G0[base] + G1[base] + b_gru[j];
                float g1 = G0[base + 1024] + G1[base + 1024] + b_gru[j + 1024];
                float g2 = G0[base + 2048] + G1[base + 2048] + b_gru[j + 2048];
                gv[u][0] = g0; gv[u][1] = g1; gv[u][2] = g2;
                s1 += g0 + g1 + g2;
                s2 += g0 * g0 + g1 * g1 + g2 * g2;
            }
#pragma unroll
            for (int o = 32; o > 0; o >>= 1) {
                s1 += __shfl_down(s1, o, 64);
                s2 += __shfl_down(s2, o, 64);
            }
            if ((tid & 63) == 0) { s_red1[tid >> 6] = s1; s_red2[tid >> 6] = s2; }
            __syncthreads();
            if (tid == 0) {
                float a = 0.f, c = 0.f;
                for (int i = 0; i < 8; i++) { a += s_red1[i]; c += s_red2[i]; }
                float mean = a / 3072.f;
                float var = c / 3072.f - mean * mean;
                s_mv[0] = mean; s_mv[1] = rsqrtf(var + 1e-5f);
            }
            __syncthreads();
            float mean = s_mv[0], rstd = s_mv[1];
#pragma unroll
            for (int u = 0; u < 2; ++u) {
                int j = tid + u * NT_;
                float n0 = (gv[u][0] - mean) * rstd * ln_g[j] + ln_b[j];
                float n1 = (gv[u][1] - mean) * rstd * ln_g[j + 1024] + ln_b[j + 1024];
                float n2 = (gv[u][2] - mean) * rstd * ln_g[j + 2048] + ln_b[j + 2048];
                float reset = sigmoid_f(n0);
                float cand = tanhf(reset * n1);
                float upd = sigmoid_f(n2 - 1.f);   // UPDATE_BIAS = -1
                float dn = upd * cand + (1.f - upd) * s_dm[j];
                s_deter[j] = dn;
                unsigned short dbf = f2bf(dn);
                dnew_bf[(size_t)b * 1024 + j] = dbf;
                dcat[(size_t)b * 2560 + j] = dbf;
                out[((size_t)b * T_ + t) * OUTW_ + 192 + j] = dn;
            }
        }
        gbar(bar_cnt, bar_gen);

        // ---- GEMM2: ens head (K=1024, split 2) + obs head (K=2560, split 4)
        {
            int e = ens_idx[t];
            if (bb < 64) {            // ens: blocks c, c+32 same XCD
                int ks = bb >> 5;
                int col0 = (bb & 31) * 32;
                int row0 = wid * 32;
                f32x4 acc[2][2];
#pragma unroll
                for (int i = 0; i < 2; i++)
#pragma unroll
                    for (int j = 0; j < 2; j++) { f32x4 z = {0.f,0.f,0.f,0.f}; acc[i][j] = z; }
                mfma22(dnew_bf + ks * 512, 1024,
                       Wt_ens + (size_t)e * 1048576 + ks * 512, 1024, 16, row0, col0, acc);
                store22(ks ? h1 : h0, 1024, row0, col0, acc);
            } else if (bb >= 128) {   // obs: blocks 128+c, +32, +64, +96 same XCD
                int i2 = bb - 128;
                int ks = i2 >> 5;     // 0..3, K-quarter of 640
                int col0 = (i2 & 31) * 32;
                int row0 = wid * 32;
                f32x4 acc[2][2];
#pragma unroll
                for (int i = 0; i < 2; i++)
#pragma unroll
                    for (int j = 0; j < 2; j++) { f32x4 z = {0.f,0.f,0.f,0.f}; acc[i][j] = z; }
                mfma22(dcat + ks * 640, 2560, Wt_obs + ks * 640, 2560, 20, row0, col0, acc);
                float* dst = (ks == 0) ? xo0 : (ks == 1) ? xo1 : (ks == 2) ? xo2 : xo3;
                store22(dst, 1024, row0, col0, acc);
            }
        }
        gbar(bar_cnt, bar_gen);

        // ---- dist layers + output + next-step prep: block b <-> row b ------
        {
            const int b = bb;
            int e = ens_idx[t];
            for (int i = tid; i < 1024; i += NT_) {
                size_t bi = (size_t)b * 1024 + i;
                s_h[i] = elu_f(h0[bi] + h1[bi] + b_ens[e * 1024 + i]);
                s_xo[i] = elu_f(xo0[bi] + xo1[bi] + xo2[bi] + xo3[bi] + b_obs[i]);
            }
            __syncthreads();
            {
                int c = tid & 127, kp = tid >> 7;
                int k0 = kp * 256;
                const float* W;
                const float* src;
                if (c < 64) { W = Wed + (size_t)e * 65536 + c; src = s_h; }
                else        { W = Wod + (c - 64);              src = s_xo; }
                float a2 = 0.f;
                for (int k = k0; k < k0 + 256; ++k) a2 += src[k] * W[(size_t)k * 64];
                s_acc[tid] = a2;
            }
            __syncthreads();
            if (tid < 128) {
                float tot = s_acc[tid] + s_acc[tid + 128] + s_acc[tid + 256] + s_acc[tid + 384];
                tot += (tid < 64) ? bed[e * 64 + tid] : bod[tid - 64];
                s_tot[tid] = tot;
            }
            __syncthreads();
            if (tid < 32) {
                float pm = s_tot[tid];
                float ps = softplus_f(s_tot[32 + tid]) + 0.1f;
                float om = s_tot[64 + tid];
                float os = softplus_f(s_tot[96 + tid]) + 0.1f;
                size_t bt = (size_t)b * T_ + t;
                float prior = pm + ps * eps_prior[bt * 32 + tid];
                float post = om + os * eps_post[bt * 32 + tid];
                float* o = out + bt * OUTW_;
                o[tid] = om; o[32 + tid] = os; o[64 + tid] = post;
                o[96 + tid] = pm; o[128 + tid] = ps; o[160 + tid] = prior;
                s_stoch[tid] = post;
            }
            int tn = t + 1;
            if (tn < T_) {
                __syncthreads();
                float m = is_first[b * T_ + tn] ? 0.f : 1.f;
                if (tid < ACT_) s_am[tid] = action[((size_t)b * T_ + tn) * ACT_ + tid] * m;
                __syncthreads();
                for (int n = tid; n < 1024; n += NT_) {
                    float sacc = 0.f;
#pragma unroll
                    for (int k = 0; k < 32; k++) sacc += s_stoch[k] * W_inp[k * 1024 + n];
                    float a = b_inp[n] + m * sacc;
#pragma unroll
                    for (int k = 0; k < ACT_; k++) a += s_am[k] * W_inp[(32 + k) * 1024 + n];
                    xcat[(size_t)b * 2048 + n] = f2bf(elu_f(a));
                    float dm = s_deter[n] * m;
                    s_dm[n] = dm;
                    xcat[(size_t)b * 2048 + 1024 + n] = f2bf(dm);
                }
                for (int j = tid; j < 1536; j += NT_)
                    dcat[(size_t)b * 2560 + 1024 + j] =
                        f2bf(embed[((size_t)b * T_ + tn) * 1536 + j]);
            }
        }
        gbar(bar_cnt, bar_gen);
    }
}

extern "C" void kernel_launch(void* const* d_in, const int* in_sizes, int n_in,
                              void* d_out, int out_size, void* d_ws, size_t ws_size,
                              hipStream_t stream) {
    const float* embed      = (const float*)d_in[0];
    const float* action     = (const float*)d_in[1];
    const float* eps_post   = (const float*)d_in[2];
    const float* eps_prior  = (const float*)d_in[3];
    const unsigned char* is_first = (const unsigned char*)d_in[4];
    const int* ens_idx      = (const int*)d_in[5];
    const float* W_gru      = (const float*)d_in[6];
    const float* b_gru      = (const float*)d_in[7];
    const float* ln_g       = (const float*)d_in[8];
    const float* ln_b       = (const float*)d_in[9];
    const float* W_inp      = (const float*)d_in[10];
    const float* b_inp      = (const float*)d_in[11];
    const float* W_obs      = (const float*)d_in[12];
    const float* b_obs      = (const float*)d_in[13];
    const float* W_ens      = (const float*)d_in[14];
    const float* b_ens      = (const float*)d_in[15];
    const float* W_obs_dist = (const float*)d_in[16];
    const float* b_obs_dist = (const float*)d_in[17];
    const float* W_ens_dist = (const float*)d_in[18];
    const float* b_ens_dist = (const float*)d_in[19];
    float* out = (float*)d_out;

    char* p = (char*)d_ws;
    auto take = [&](size_t bytes) -> char* {
        char* r = p;
        p += (bytes + 255) & ~(size_t)255;
        return r;
    };
    unsigned* bar_mem = (unsigned*)take(256);          // cnt @0, gen @128B
    unsigned short* Wt_gru = (unsigned short*)take((size_t)3072 * 2048 * 2);
    unsigned short* Wt_obs = (unsigned short*)take((size_t)1024 * 2560 * 2);
    unsigned short* Wt_ens = (unsigned short*)take((size_t)5 * 1024 * 1024 * 2);
    unsigned short* xcat    = (unsigned short*)take((size_t)B_ * 2048 * 2);
    unsigned short* dcat    = (unsigned short*)take((size_t)B_ * 2560 * 2);
    unsigned short* dnew_bf = (unsigned short*)take((size_t)B_ * 1024 * 2);
    float* G0  = (float*)take((size_t)B_ * 3072 * 4);
    float* G1  = (float*)take((size_t)B_ * 3072 * 4);
    float* h0  = (float*)take((size_t)B_ * 1024 * 4);
    float* h1  = (float*)take((size_t)B_ * 1024 * 4);
    float* xo0 = (float*)take((size_t)B_ * 1024 * 4);
    float* xo1 = (float*)take((size_t)B_ * 1024 * 4);
    float* xo2 = (float*)take((size_t)B_ * 1024 * 4);
    float* xo3 = (float*)take((size_t)B_ * 1024 * 4);
    if ((size_t)(p - (char*)d_ws) > ws_size) return;   // workspace too small

    hipMemsetAsync(bar_mem, 0, 256, stream);           // zero barrier state

    unsigned* bar_cnt = bar_mem;
    unsigned* bar_gen = bar_mem + 32;                  // separate cache line

    rssm_persistent<<<dim3(GRID_), dim3(NT_), 0, stream>>>(
        embed, action, eps_post, eps_prior, is_first, ens_idx,
        W_gru, b_gru, ln_g, ln_b, W_inp, b_inp, W_obs, b_obs,
        W_ens, b_ens, W_obs_dist, b_obs_dist, W_ens_dist, b_ens_dist,
        out, bar_cnt, bar_gen,
        Wt_gru, Wt_obs, Wt_ens, xcat, dcat, dnew_bf,
        G0, G1, h0, h1, xo0, xo1, xo2, xo3);
}

// Round 3
// 10840.185 us; speedup vs baseline: 2.7359x; 2.7359x over previous
//
#include <hip/hip_runtime.h>
#include <hip/hip_bf16.h>

// EnsembleRSSM observe scan — persistent kernel, fence-free synchronization.
// Cross-block data: system-scope (sc0 sc1) relaxed atomics -> coherent at L3,
// no L2 writeback/invalidate (round-2 killer). Weights: plain loads, each
// weight byte read by exactly ONE block -> L2-resident across steps.
// Barrier: per-wave vmcnt(0) drain + hierarchical relaxed agent atomics.
// Grid 256 x 512thr, LDS < 64KB (2 blocks/CU fit -> no residency deadlock).

#define B_ 256
#define T_ 64
#define ACT_ 6
#define OUTW_ 1216
#define GRID_ 256
#define NT_ 512

typedef __attribute__((ext_vector_type(8))) short bf16x8;
typedef __attribute__((ext_vector_type(4))) float f32x4;
typedef unsigned long long u64;
typedef unsigned int u32;
typedef unsigned short u16;

__device__ inline u16 f2bf(float x) {
    union { float f; u32 u; } v; v.f = x;
    u32 r = v.u + 0x7fffu + ((v.u >> 16) & 1u);
    return (u16)(r >> 16);
}
__device__ inline u32 pack2(u16 lo, u16 hi) { return (u32)lo | ((u32)hi << 16); }
__device__ inline float2 q2f2(u64 q) { union { u64 u; float2 f; } v; v.u = q; return v.f; }
__device__ inline float softplus_f(float x) { return x > 20.f ? x : log1pf(expf(x)); }
__device__ inline float sigmoid_f(float x) { return 1.f / (1.f + expf(-x)); }
__device__ inline float elu_f(float x) { return x > 0.f ? x : expm1f(x); }

// system-scope (L3-coherent) relaxed accessors — no cache maintenance emitted
template <typename T>
__device__ inline T sys_ld(const T* p) {
    return __hip_atomic_load((T*)p, __ATOMIC_RELAXED, __HIP_MEMORY_SCOPE_SYSTEM);
}
template <typename T>
__device__ inline void sys_st(T* p, T v) {
    __hip_atomic_store(p, v, __ATOMIC_RELAXED, __HIP_MEMORY_SCOPE_SYSTEM);
}
__device__ inline u32 agent_add(u32* p, u32 v) {
    return __hip_atomic_fetch_add(p, v, __ATOMIC_RELAXED, __HIP_MEMORY_SCOPE_AGENT);
}
__device__ inline u32 agent_ld(u32* p) {
    return __hip_atomic_load(p, __ATOMIC_RELAXED, __HIP_MEMORY_SCOPE_AGENT);
}
__device__ inline void agent_st(u32* p, u32 v) {
    __hip_atomic_store(p, v, __ATOMIC_RELAXED, __HIP_MEMORY_SCOPE_AGENT);
}
__device__ inline int get_xcc() {
    return (int)(__builtin_amdgcn_s_getreg((3 << 11) | 20) & 7);  // HW_REG_XCC_ID
}

// fence-free grid barrier: every wave drains its own VMEM, then hierarchical
// arrival (8 groups of exactly 32 via blockIdx&7) + generation spin.
__device__ inline void gbar(u32* cntX, u32* cnt8, u32* gen, int Xa) {
    asm volatile("s_waitcnt vmcnt(0)" ::: "memory");  // per-wave drain
    __syncthreads();
    if (threadIdx.x == 0) {
        u32 g = agent_ld(gen);
        u32 a = agent_add(&cntX[Xa * 32], 1u);
        if (a == 31u) {
            agent_st(&cntX[Xa * 32], 0u);
            u32 b = agent_add(cnt8, 1u);
            if (b == 7u) {
                agent_st(cnt8, 0u);
                agent_st(gen, g + 1u);
            }
        }
        while (agent_ld(gen) == g) __builtin_amdgcn_s_sleep(2);
    }
    __syncthreads();
}

__global__ __launch_bounds__(NT_)
void rssm_persistent(
    const float* __restrict__ embed, const float* __restrict__ action,
    const float* __restrict__ eps_post, const float* __restrict__ eps_prior,
    const unsigned char* __restrict__ is_first, const int* __restrict__ ens_idx,
    const float* __restrict__ W_gru, const float* __restrict__ b_gru,
    const float* __restrict__ ln_g, const float* __restrict__ ln_b,
    const float* __restrict__ W_inp, const float* __restrict__ b_inp,
    const float* __restrict__ W_obs, const float* __restrict__ b_obs,
    const float* __restrict__ W_ens, const float* __restrict__ b_ens,
    const float* __restrict__ Wod, const float* __restrict__ bod,
    const float* __restrict__ Wed, const float* __restrict__ bed,
    float* __restrict__ out,
    u32* ctrl,                       // [0..255] cntX, [256..287] cnt8, [320] gen, [512..] xcc_cnt
    u16* __restrict__ Wt_gru, u16* __restrict__ Wt_obs, u16* __restrict__ Wt_ens,
    u16* __restrict__ xcat, u16* __restrict__ dcat, u16* __restrict__ dnew_bf,
    float* __restrict__ G, float* __restrict__ h_f, float* __restrict__ xo_f)
{
    __shared__ float s_tile[64][33];
    __shared__ u64 stage_q[32 * 130];          // 33280 B K-chunk staging (512 k x 32 rows)
    __shared__ float s_deter[1024], s_dm[1024];
    __shared__ float s_h[1024], s_xo[1024];
    __shared__ float s_acc[512], s_tot[128];
    __shared__ float s_red1[8], s_red2[8], s_mv[2];
    __shared__ float s_stoch[32], s_am[8];
    __shared__ int s_info[2];

    const int tid = threadIdx.x;
    const int bb = blockIdx.x;
    const int Xa = bb & 7;                     // barrier arrival group (exactly 32 each)
    u32* cntX = ctrl;
    u32* cnt8 = ctrl + 256;
    u32* gen  = ctrl + 320;
    u32* xcc_cnt = ctrl + 512;                 // 8 counters spaced 32 u32

    // ---------------- setup: weight transpose->bf16 [N][K], xcc rank -------
    {
        const int tx = tid & 31, ty = tid >> 5;   // 32 x 16
        for (int task = bb; task < 6912; task += GRID_) {
            const float* src; u32* dstw; int K, N, kt, nt2;
            if (task < 3072) { src = W_gru; dstw = (u32*)Wt_gru; K = 2048; N = 3072; kt = task / 96; nt2 = task % 96; }
            else if (task < 4352) { int i = task - 3072; src = W_obs; dstw = (u32*)Wt_obs; K = 2560; N = 1024; kt = i >> 5; nt2 = i & 31; }
            else { int i = task - 4352; int e = i >> 9; int r2 = i & 511;
                   src = W_ens + (size_t)e * 1048576; dstw = (u32*)(Wt_ens + (size_t)e * 1048576);
                   K = 1024; N = 1024; kt = r2 >> 5; nt2 = r2 & 31; }
            const int k0 = kt * 64, n0 = nt2 * 32;
            for (int k = ty; k < 64; k += 16) s_tile[k][tx] = src[(size_t)(k0 + k) * N + n0 + tx];
            __syncthreads();
            for (int n = ty; n < 32; n += 16) {
                u32 d = pack2(f2bf(s_tile[2 * tx][n]), f2bf(s_tile[2 * tx + 1][n]));
                sys_st(&dstw[((size_t)(n0 + n) * K + k0) / 2 + tx], d);
            }
            __syncthreads();
        }
        if (tid == 0) {
            int x = get_xcc();
            u32 rank = agent_add(&xcc_cnt[x * 32], 1u);
            s_info[0] = x; s_info[1] = (int)rank;
        }
    }
    gbar(cntX, cnt8, gen, Xa);                 // transposes + ranks visible

    // slot = permutation of 0..255 grouping same-XCD blocks contiguously
    if (tid == 0) {
        int x = s_info[0]; int slot = s_info[1];
        for (int i = 0; i < x; i++) slot += (int)agent_ld(&xcc_cnt[i * 32]);
        s_info[0] = slot;
    }
    __syncthreads();
    const int slot = s_info[0];
    const int X = slot >> 5, r = slot & 31;
    const int lane = tid & 63, wv = tid >> 6;
    const int lr = lane & 15, q = lane >> 4;

    // ---------------- prep for step tn (row = slot), uses LDS state ---------
    auto prep = [&](int tn) {
        __syncthreads();
        float m = is_first[slot * T_ + tn] ? 0.f : 1.f;
        if (tid < ACT_) s_am[tid] = action[((size_t)slot * T_ + tn) * ACT_ + tid] * m;
        __syncthreads();
        {
            const int n0 = 2 * tid, n1 = 2 * tid + 1;
            float sa0 = 0.f, sa1 = 0.f;
#pragma unroll
            for (int k = 0; k < 32; k++) {
                float s = s_stoch[k];
                sa0 += s * W_inp[k * 1024 + n0];
                sa1 += s * W_inp[k * 1024 + n1];
            }
            float a0 = b_inp[n0] + m * sa0, a1 = b_inp[n1] + m * sa1;
#pragma unroll
            for (int k = 0; k < ACT_; k++) {
                float am = s_am[k];
                a0 += am * W_inp[(32 + k) * 1024 + n0];
                a1 += am * W_inp[(32 + k) * 1024 + n1];
            }
            sys_st(&((u32*)xcat)[slot * 1024 + tid], pack2(f2bf(elu_f(a0)), f2bf(elu_f(a1))));
            float dm0 = s_deter[n0] * m, dm1 = s_deter[n1] * m;
            s_dm[n0] = dm0; s_dm[n1] = dm1;
            sys_st(&((u32*)xcat)[slot * 1024 + 512 + tid], pack2(f2bf(dm0), f2bf(dm1)));
        }
        for (int d = tid; d < 768; d += NT_) {
            float2 ev = *(const float2*)&embed[((size_t)slot * T_ + tn) * 1536 + 2 * d];
            sys_st(&((u32*)dcat)[slot * 1280 + 512 + d], pack2(f2bf(ev.x), f2bf(ev.y)));
        }
    };

    // ---------------- step 0 prep (zero state) ------------------------------
    for (int i = tid; i < 1024; i += NT_) { s_deter[i] = 0.f; s_dm[i] = 0.f; }
    if (tid < 32) s_stoch[tid] = 0.f;
    prep(0);
    gbar(cntX, cnt8, gen, Xa);

    // ---------------- main scan ---------------------------------------------
    for (int t = 0; t < T_; ++t) {
        // ==== Phase A: G = xcat[256,2048] @ W_gru -> [256,3072] =============
        // 192 tasks: 24 col-tiles(128) x 8 row-groups(32); X owns 3 col-tiles.
        if (r < 24) {
            const int ct = X * 3 + (r % 3);
            const int rg = r / 3;
            const int col = ct * 128 + wv * 16 + lr;
            const u16* bp = Wt_gru + (size_t)col * 2048 + q * 8;
            const u64* xq = (const u64*)xcat;              // 512 qwords/row
            const u16* aL = (const u16*)stage_q;           // stride 520 shorts
            f32x4 acc0 = {0.f, 0.f, 0.f, 0.f}, acc1 = {0.f, 0.f, 0.f, 0.f};
            for (int ch = 0; ch < 4; ch++) {               // K chunks of 512
                __syncthreads();
#pragma unroll
                for (int i = 0; i < 8; i++) {
                    int idx = tid + i * NT_;
                    int row = idx >> 7, kq = idx & 127;
                    stage_q[row * 130 + kq] = sys_ld(&xq[(size_t)(rg * 32 + row) * 512 + ch * 128 + kq]);
                }
                __syncthreads();
                const u16* bp2 = bp + ch * 512;
                for (int k = 0; k < 512; k += 32) {
                    bf16x8 b0 = *(const bf16x8*)(bp2 + k);
                    bf16x8 a0 = *(const bf16x8*)(aL + (size_t)lr * 520 + k + q * 8);
                    bf16x8 a1 = *(const bf16x8*)(aL + (size_t)(16 + lr) * 520 + k + q * 8);
                    acc0 = __builtin_amdgcn_mfma_f32_16x16x32_bf16(a0, b0, acc0, 0, 0, 0);
                    acc1 = __builtin_amdgcn_mfma_f32_16x16x32_bf16(a1, b0, acc1, 0, 0, 0);
                }
            }
            float* Gp = G + (size_t)(rg * 32) * 3072 + col;
#pragma unroll
            for (int v = 0; v < 4; v++) {
                sys_st(&Gp[(size_t)(q * 4 + v) * 3072], acc0[v]);
                sys_st(&Gp[(size_t)(16 + q * 4 + v) * 3072], acc1[v]);
            }
        }
        gbar(cntX, cnt8, gen, Xa);

        // ==== Phase B: LN + GRU gates, row = slot ===========================
        {
            const u64* Gq = (const u64*)(G + (size_t)slot * 3072);
            u64 q0 = sys_ld(&Gq[tid]);
            u64 q1 = sys_ld(&Gq[tid + 512]);
            u64 q2 = sys_ld(&Gq[tid + 1024]);
            float2 p0 = q2f2(q0), p1 = q2f2(q1), p2 = q2f2(q2);
            const float2 bg0 = ((const float2*)b_gru)[tid];
            const float2 bg1 = ((const float2*)b_gru)[tid + 512];
            const float2 bg2 = ((const float2*)b_gru)[tid + 1024];
            float g00 = p0.x + bg0.x, g01 = p0.y + bg0.y;
            float g10 = p1.x + bg1.x, g11 = p1.y + bg1.y;
            float g20 = p2.x + bg2.x, g21 = p2.y + bg2.y;
            float s1 = g00 + g01 + g10 + g11 + g20 + g21;
            float s2 = g00 * g00 + g01 * g01 + g10 * g10 + g11 * g11 + g20 * g20 + g21 * g21;
#pragma unroll
            for (int o = 32; o > 0; o >>= 1) { s1 += __shfl_down(s1, o, 64); s2 += __shfl_down(s2, o, 64); }
            if (lane == 0) { s_red1[wv] = s1; s_red2[wv] = s2; }
            __syncthreads();
            if (tid == 0) {
                float a = 0.f, c = 0.f;
                for (int i = 0; i < 8; i++) { a += s_red1[i]; c += s_red2[i]; }
                float mean = a / 3072.f;
                s_mv[0] = mean; s_mv[1] = rsqrtf(c / 3072.f - mean * mean + 1e-5f);
            }
            __syncthreads();
            const float mean = s_mv[0], rstd = s_mv[1];
            const float2 lg0 = ((const float2*)ln_g)[tid],        lb0 = ((const float2*)ln_b)[tid];
            const float2 lg1 = ((const float2*)ln_g)[tid + 512],  lb1 = ((const float2*)ln_b)[tid + 512];
            const float2 lg2 = ((const float2*)ln_g)[tid + 1024], lb2 = ((const float2*)ln_b)[tid + 1024];
            float n00 = (g00 - mean) * rstd * lg0.x + lb0.x, n01 = (g01 - mean) * rstd * lg0.y + lb0.y;
            float n10 = (g10 - mean) * rstd * lg1.x + lb1.x, n11 = (g11 - mean) * rstd * lg1.y + lb1.y;
            float n20 = (g20 - mean) * rstd * lg2.x + lb2.x, n21 = (g21 - mean) * rstd * lg2.y + lb2.y;
            float c0 = tanhf(sigmoid_f(n00) * n10), c1 = tanhf(sigmoid_f(n01) * n11);
            float u0 = sigmoid_f(n20 - 1.f), u1 = sigmoid_f(n21 - 1.f);
            float dn0 = u0 * c0 + (1.f - u0) * s_dm[2 * tid];
            float dn1 = u1 * c1 + (1.f - u1) * s_dm[2 * tid + 1];
            s_deter[2 * tid] = dn0; s_deter[2 * tid + 1] = dn1;
            u32 dpk = pack2(f2bf(dn0), f2bf(dn1));
            sys_st(&((u32*)dnew_bf)[slot * 512 + tid], dpk);
            sys_st(&((u32*)dcat)[slot * 1280 + tid], dpk);
            float2 dv; dv.x = dn0; dv.y = dn1;
            *(float2*)&out[((size_t)slot * T_ + t) * OUTW_ + 192 + 2 * tid] = dv;
        }
        gbar(cntX, cnt8, gen, Xa);

        // ==== Phase C: heads.  ens: 16ct(64)x8rg; obs: 16ct(64)x8rg ========
        {
            const int e = ens_idx[t];
            const int mi = wv & 1, ni = wv >> 1;
            if (r < 16) {
                const int ct = X * 2 + (r & 1), rg = r >> 1;
                const int col = ct * 64 + ni * 16 + lr;
                const u64* dq = (const u64*)dnew_bf;       // 256 qwords/row
                const u16* aL = (const u16*)stage_q;
                const u16* bp = Wt_ens + (size_t)e * 1048576 + (size_t)col * 1024 + q * 8;
                f32x4 acc = {0.f, 0.f, 0.f, 0.f};
                for (int ch = 0; ch < 2; ch++) {
                    __syncthreads();
#pragma unroll
                    for (int i = 0; i < 8; i++) {
                        int idx = tid + i * NT_;
                        int row = idx >> 7, kq = idx & 127;
                        stage_q[row * 130 + kq] = sys_ld(&dq[(size_t)(rg * 32 + row) * 256 + ch * 128 + kq]);
                    }
                    __syncthreads();
                    const u16* bp2 = bp + ch * 512;
                    for (int k = 0; k < 512; k += 32) {
                        bf16x8 b0 = *(const bf16x8*)(bp2 + k);
                        bf16x8 a0 = *(const bf16x8*)(aL + (size_t)(mi * 16 + lr) * 520 + k + q * 8);
                        acc = __builtin_amdgcn_mfma_f32_16x16x32_bf16(a0, b0, acc, 0, 0, 0);
                    }
                }
                float bias = b_ens[e * 1024 + col];
                float* hp = h_f + (size_t)(rg * 32 + mi * 16) * 1024 + col;
#pragma unroll
                for (int v = 0; v < 4; v++) sys_st(&hp[(size_t)(q * 4 + v) * 1024], elu_f(acc[v] + bias));
            } else {
                const int rr = r - 16;
                const int ct = X * 2 + (rr & 1), rg = rr >> 1;
                const int col = ct * 64 + ni * 16 + lr;
                const u64* cq = (const u64*)dcat;          // 640 qwords/row
                const u16* aL = (const u16*)stage_q;
                const u16* bp = Wt_obs + (size_t)col * 2560 + q * 8;
                f32x4 acc = {0.f, 0.f, 0.f, 0.f};
                for (int ch = 0; ch < 5; ch++) {
                    __syncthreads();
#pragma unroll
                    for (int i = 0; i < 8; i++) {
                        int idx = tid + i * NT_;
                        int row = idx >> 7, kq = idx & 127;
                        stage_q[row * 130 + kq] = sys_ld(&cq[(size_t)(rg * 32 + row) * 640 + ch * 128 + kq]);
                    }
                    __syncthreads();
                    const u16* bp2 = bp + ch * 512;
                    for (int k = 0; k < 512; k += 32) {
                        bf16x8 b0 = *(const bf16x8*)(bp2 + k);
                        bf16x8 a0 = *(const bf16x8*)(aL + (size_t)(mi * 16 + lr) * 520 + k + q * 8);
                        acc = __builtin_amdgcn_mfma_f32_16x16x32_bf16(a0, b0, acc, 0, 0, 0);
                    }
                }
                float bias = b_obs[col];
                float* xp = xo_f + (size_t)(rg * 32 + mi * 16) * 1024 + col;
#pragma unroll
                for (int v = 0; v < 4; v++) sys_st(&xp[(size_t)(q * 4 + v) * 1024], elu_f(acc[v] + bias));
            }
        }
        gbar(cntX, cnt8, gen, Xa);

        // ==== Phase D: dist layers + output + next-step prep, row = slot ===
        {
            const int e = ens_idx[t];
            {
                u64 v0 = sys_ld(&((const u64*)(h_f + (size_t)slot * 1024))[tid]);
                u64 v1 = sys_ld(&((const u64*)(xo_f + (size_t)slot * 1024))[tid]);
                float2 a = q2f2(v0), b2 = q2f2(v1);
                s_h[2 * tid] = a.x;  s_h[2 * tid + 1] = a.y;
                s_xo[2 * tid] = b2.x; s_xo[2 * tid + 1] = b2.y;
            }
            __syncthreads();
            {
                const int c = tid & 127, kp = tid >> 7;
                const int k0 = kp * 256;
                const float* W; const float* src;
                if (c < 64) { W = Wed + (size_t)e * 65536 + c; src = s_h; }
                else        { W = Wod + (c - 64);              src = s_xo; }
                float a2 = 0.f;
                for (int k = k0; k < k0 + 256; ++k) a2 += src[k] * W[(size_t)k * 64];
                s_acc[tid] = a2;
            }
            __syncthreads();
            if (tid < 128) {
                float tot = s_acc[tid] + s_acc[tid + 128] + s_acc[tid + 256] + s_acc[tid + 384];
                tot += (tid < 64) ? bed[e * 64 + tid] : bod[tid - 64];
                s_tot[tid] = tot;
            }
            __syncthreads();
            if (tid < 32) {
                float pm = s_tot[tid];
                float ps = softplus_f(s_tot[32 + tid]) + 0.1f;
                float om = s_tot[64 + tid];
                float os = softplus_f(s_tot[96 + tid]) + 0.1f;
                size_t bt = (size_t)slot * T_ + t;
                float prior = pm + ps * eps_prior[bt * 32 + tid];
                float post = om + os * eps_post[bt * 32 + tid];
                float* o = out + bt * OUTW_;
                o[tid] = om; o[32 + tid] = os; o[64 + tid] = post;
                o[96 + tid] = pm; o[128 + tid] = ps; o[160 + tid] = prior;
                s_stoch[tid] = post;
            }
            if (t + 1 < T_) prep(t + 1);
        }
        gbar(cntX, cnt8, gen, Xa);
    }
}

extern "C" void kernel_launch(void* const* d_in, const int* in_sizes, int n_in,
                              void* d_out, int out_size, void* d_ws, size_t ws_size,
                              hipStream_t stream) {
    const float* embed      = (const float*)d_in[0];
    const float* action     = (const float*)d_in[1];
    const float* eps_post   = (const float*)d_in[2];
    const float* eps_prior  = (const float*)d_in[3];
    const unsigned char* is_first = (const unsigned char*)d_in[4];
    const int* ens_idx      = (const int*)d_in[5];
    const float* W_gru      = (const float*)d_in[6];
    const float* b_gru      = (const float*)d_in[7];
    const float* ln_g       = (const float*)d_in[8];
    const float* ln_b       = (const float*)d_in[9];
    const float* W_inp      = (const float*)d_in[10];
    const float* b_inp      = (const float*)d_in[11];
    const float* W_obs      = (const float*)d_in[12];
    const float* b_obs      = (const float*)d_in[13];
    const float* W_ens      = (const float*)d_in[14];
    const float* b_ens      = (const float*)d_in[15];
    const float* W_obs_dist = (const float*)d_in[16];
    const float* b_obs_dist = (const float*)d_in[17];
    const float* W_ens_dist = (const float*)d_in[18];
    const float* b_ens_dist = (const float*)d_in[19];
    float* out = (float*)d_out;

    char* p = (char*)d_ws;
    auto take = [&](size_t bytes) -> char* {
        char* r = p;
        p += (bytes + 255) & ~(size_t)255;
        return r;
    };
    u32* ctrl = (u32*)take(4096);
    u16* Wt_gru = (u16*)take((size_t)3072 * 2048 * 2);
    u16* Wt_obs = (u16*)take((size_t)1024 * 2560 * 2);
    u16* Wt_ens = (u16*)take((size_t)5 * 1024 * 1024 * 2);
    u16* xcat    = (u16*)take((size_t)B_ * 2048 * 2);
    u16* dcat    = (u16*)take((size_t)B_ * 2560 * 2);
    u16* dnew_bf = (u16*)take((size_t)B_ * 1024 * 2);
    float* G    = (float*)take((size_t)B_ * 3072 * 4);
    float* h_f  = (float*)take((size_t)B_ * 1024 * 4);
    float* xo_f = (float*)take((size_t)B_ * 1024 * 4);
    if ((size_t)(p - (char*)d_ws) > ws_size) return;

    hipMemsetAsync(ctrl, 0, 4096, stream);     // barrier + xcc counters

    rssm_persistent<<<dim3(GRID_), dim3(NT_), 0, stream>>>(
        embed, action, eps_post, eps_prior, is_first, ens_idx,
        W_gru, b_gru, ln_g, ln_b, W_inp, b_inp, W_obs, b_obs,
        W_ens, b_ens, W_obs_dist, b_obs_dist, W_ens_dist, b_ens_dist,
        out, ctrl, Wt_gru, Wt_obs, Wt_ens, xcat, dcat, dnew_bf, G, h_f, xo_f);
}